// Round 1
// baseline (387.179 us; speedup 1.0000x reference)
//
#include <hip/hip_runtime.h>
#include <hip/hip_bf16.h>
#include <float.h>

// Problem constants (from reference): B=32, L=131072, WIDTH=25, PAD=12.
#define ROWS 32
#define LEN  131072
#define PADW 12
#define NPK  16384   // max peaks/row is ceil(131072/13)=10083; 16384 gives headroom
#define BLK1 1024    // threads for peak kernel (16 waves)

// ---------------------------------------------------------------------------
// Kernel 1: per (signal,row) peak detection + stable compaction.
// Grid: 64 blocks (blockIdx 0..31 = preds rows, 32..63 = labels rows).
// Peak condition matching jnp.argmax(window)==PAD (first-max tie-break):
//   x[t] >  x[t-j]  for j=1..12   (strictly greater than earlier elements)
//   x[t] >= x[t+j]  for j=1..12
// Out-of-range treated as -FLT_MAX (== jnp.finfo(f32).min padding).
// Compaction is chunk-sequential + in-chunk rank => output ascending (sorted).
// ---------------------------------------------------------------------------
__global__ __launch_bounds__(BLK1) void peaks_kernel(
    const float* __restrict__ preds, const float* __restrict__ labels,
    float* __restrict__ peaks, int* __restrict__ counts)
{
    const int bid = blockIdx.x;       // 0..63
    const int sig = bid >> 5;         // 0=preds, 1=labels
    const int row = bid & 31;
    const float* __restrict__ x = (sig ? labels : preds) + (size_t)row * LEN;
    float* __restrict__ pk = peaks + (size_t)bid * NPK;

    __shared__ float s[BLK1 + 2 * PADW];
    __shared__ int wave_cnt[BLK1 / 64];
    __shared__ int base_off;

    const int tid  = threadIdx.x;
    const int lane = tid & 63;
    const int wave = tid >> 6;
    if (tid == 0) base_off = 0;
    __syncthreads();

    for (int chunk = 0; chunk < LEN; chunk += BLK1) {
        // stage [chunk-12, chunk+BLK1+12)
        for (int i = tid; i < BLK1 + 2 * PADW; i += BLK1) {
            int g = chunk + i - PADW;
            s[i] = (g >= 0 && g < LEN) ? x[g] : -FLT_MAX;
        }
        __syncthreads();

        const float v = s[tid + PADW];
        bool peak = true;
        #pragma unroll
        for (int j = 1; j <= PADW; ++j) peak = peak && (s[tid + PADW - j] <  v);
        #pragma unroll
        for (int j = 1; j <= PADW; ++j) peak = peak && (s[tid + PADW + j] <= v);

        unsigned long long mask = __ballot(peak);
        int rank = __popcll(mask & ((1ull << lane) - 1ull));
        if (lane == 0) wave_cnt[wave] = __popcll(mask);
        __syncthreads();

        int wbase = 0;
        for (int w = 0; w < wave; ++w) wbase += wave_cnt[w];
        if (peak) pk[base_off + wbase + rank] = (float)(chunk + tid);
        __syncthreads();          // all reads of base_off done

        if (tid == 0) {
            int tot = 0;
            for (int w = 0; w < BLK1 / 64; ++w) tot += wave_cnt[w];
            base_off += tot;
        }
        __syncthreads();          // update visible before next iteration
    }
    if (tid == 0) counts[bid] = base_off;
}

// ---------------------------------------------------------------------------
// Kernel 2: per-row back-aligned abs-diff sum.
// sorted(where(is_peak,pos,0)) = [0]*(L-m) ++ P ; aligning from the back:
//   sum_j | (j<m ? P[m-1-j] : 0) - (j<n ? Q[n-1-j] : 0) |  for j < max(m,n)
// ---------------------------------------------------------------------------
__global__ __launch_bounds__(256) void rowsum_kernel(
    const float* __restrict__ peaks, const int* __restrict__ counts,
    float* __restrict__ row_sums)
{
    const int row = blockIdx.x;
    const float* __restrict__ P = peaks + (size_t)row * NPK;
    const float* __restrict__ Q = peaks + (size_t)(ROWS + row) * NPK;
    const int m = counts[row];
    const int n = counts[ROWS + row];
    const int mx = m > n ? m : n;

    float part = 0.0f;
    for (int j = threadIdx.x; j < mx; j += 256) {
        float a = (j < m) ? P[m - 1 - j] : 0.0f;
        float b = (j < n) ? Q[n - 1 - j] : 0.0f;
        part += fabsf(a - b);
    }

    __shared__ float red[256];
    red[threadIdx.x] = part;
    __syncthreads();
    for (int sft = 128; sft > 0; sft >>= 1) {
        if (threadIdx.x < sft) red[threadIdx.x] += red[threadIdx.x + sft];
        __syncthreads();
    }
    if (threadIdx.x == 0) row_sums[row] = red[0];
}

// ---------------------------------------------------------------------------
// Kernel 3: reduce 32 row sums, divide by B*L.
// ---------------------------------------------------------------------------
__global__ __launch_bounds__(64) void finalize_kernel(
    const float* __restrict__ row_sums, float* __restrict__ out)
{
    float v = (threadIdx.x < ROWS) ? row_sums[threadIdx.x] : 0.0f;
    #pragma unroll
    for (int off = 32; off > 0; off >>= 1) v += __shfl_down(v, off);
    if (threadIdx.x == 0) out[0] = v / ((float)ROWS * (float)LEN);
}

extern "C" void kernel_launch(void* const* d_in, const int* in_sizes, int n_in,
                              void* d_out, int out_size, void* d_ws, size_t ws_size,
                              hipStream_t stream)
{
    const float* preds  = (const float*)d_in[0];
    const float* labels = (const float*)d_in[1];

    // ws layout (floats): [ 64*NPK peak buffers | 64 counts (int) | 32 row_sums ]
    float* ws       = (float*)d_ws;
    float* peaks    = ws;
    int*   counts   = (int*)(ws + (size_t)2 * ROWS * NPK);
    float* row_sums = ws + (size_t)2 * ROWS * NPK + 2 * ROWS;

    peaks_kernel<<<2 * ROWS, BLK1, 0, stream>>>(preds, labels, peaks, counts);
    rowsum_kernel<<<ROWS, 256, 0, stream>>>(peaks, counts, row_sums);
    finalize_kernel<<<1, 64, 0, stream>>>(row_sums, (float*)d_out);
}

// Round 2
// 117.517 us; speedup vs baseline: 3.2947x; 3.2947x over previous
//
#include <hip/hip_runtime.h>
#include <hip/hip_bf16.h>
#include <float.h>

// Problem constants (from reference): B=32, L=131072, WIDTH=25, PAD=12.
#define ROWS 32
#define LEN  131072
#define PADW 12

#define SEG  2048            // segment length per block
#define NSEG (LEN / SEG)     // 64 segments per row-signal (== wave size, handy)
#define THR1 256             // threads in peaks kernel
#define PER  (SEG / THR1)    // 8 positions per thread
#define SLOT 160             // stride per segment peak list (max possible = 158)

// ---------------------------------------------------------------------------
// Kernel 1: segmented peak detection + per-segment stable compaction.
// Grid: 64 row-signals x 64 segments = 4096 blocks, 256 threads each.
// Peak predicate (== jnp.argmax(25-window)==PAD, first-max tie-break,
// validated in round 1):
//   x[t] >  x[t-j]  for j=1..12
//   x[t] >= x[t+j]  for j=1..12
// with out-of-range treated as -FLT_MAX.
// ---------------------------------------------------------------------------
__global__ __launch_bounds__(THR1) void peaks_seg_kernel(
    const float* __restrict__ preds, const float* __restrict__ labels,
    float* __restrict__ seg_peaks, int* __restrict__ seg_counts)
{
    const int bid    = blockIdx.x;        // 0..4095
    const int rowsig = bid >> 6;          // 0..63 (0..31 preds, 32..63 labels)
    const int seg    = bid & (NSEG - 1);
    const float* __restrict__ x =
        (rowsig >= ROWS) ? labels + (size_t)(rowsig - ROWS) * LEN
                         : preds  + (size_t)rowsig * LEN;
    const int base = seg * SEG;

    __shared__ __align__(16) float s[SEG + 2 * PADW + 8]; // [base-12, base+SEG+12)
    __shared__ int wave_tot[THR1 / 64];

    const int tid  = threadIdx.x;
    const int lane = tid & 63;
    const int wave = tid >> 6;

    // stage segment + halo (coalesced)
    for (int i = tid; i < SEG + 2 * PADW; i += THR1) {
        int g = base + i - PADW;
        s[i] = ((unsigned)g < (unsigned)LEN) ? x[g] : -FLT_MAX;
    }
    __syncthreads();

    // 32-float register window covering positions tid*8-12 .. tid*8+19
    // (s index tid*8 .. tid*8+31); tid*8 floats = 32B-aligned -> ds_read_b128
    float w[32];
    {
        const float4* s4 = (const float4*)(s + tid * PER);
        #pragma unroll
        for (int k = 0; k < 8; ++k) {
            float4 t = s4[k];
            w[4 * k + 0] = t.x; w[4 * k + 1] = t.y;
            w[4 * k + 2] = t.z; w[4 * k + 3] = t.w;
        }
    }

    unsigned pmask = 0;
    #pragma unroll
    for (int p = 0; p < PER; ++p) {
        const float v = w[p + PADW];
        bool pk = true;
        #pragma unroll
        for (int j = 1; j <= PADW; ++j) pk = pk & (w[p + PADW - j] < v);
        #pragma unroll
        for (int j = 1; j <= PADW; ++j) pk = pk & (w[p + PADW + j] <= v);
        pmask |= (unsigned)pk << p;
    }
    const int cnt = __popc(pmask);

    // wave-level inclusive scan of per-thread counts
    int inc = cnt;
    #pragma unroll
    for (int d = 1; d < 64; d <<= 1) {
        int t = __shfl_up(inc, d);
        if (lane >= d) inc += t;
    }
    if (lane == 63) wave_tot[wave] = inc;
    __syncthreads();

    int wbase = 0;
    for (int wv = 0; wv < wave; ++wv) wbase += wave_tot[wv];
    int idx = wbase + (inc - cnt);

    float* __restrict__ pk_out = seg_peaks + (size_t)bid * SLOT;
    #pragma unroll
    for (int p = 0; p < PER; ++p) {
        if (pmask & (1u << p)) {
            pk_out[idx++] = (float)(base + tid * PER + p);
        }
    }

    if (tid == 0) {
        int tot = 0;
        #pragma unroll
        for (int wv = 0; wv < THR1 / 64; ++wv) tot += wave_tot[wv];
        seg_counts[bid] = tot;
    }
}

// ---------------------------------------------------------------------------
// Kernel 2: per-row back-aligned abs-diff sum, reading peaks via
// (segment-offset prefix sums + binary search) -- no global compaction pass.
// sorted(where(is_peak,pos,0)) = [0]*(L-m) ++ P, so
//   sum = sum_j | (j<m ? P[m-1-j] : 0) - (j<n ? Q[n-1-j] : 0) |, j < max(m,n)
// Each block scales its row sum by 1/(B*L) and atomically adds to out[0].
// ---------------------------------------------------------------------------
__device__ inline float get_peak(const float* __restrict__ seg_peaks,
                                 const int* __restrict__ off, int rs, int k)
{
    // find smallest seg with off[seg+1] > k
    int lo = 0, hi = NSEG - 1;
    while (lo < hi) {
        int mid = (lo + hi) >> 1;
        if (off[mid + 1] > k) hi = mid; else lo = mid + 1;
    }
    return seg_peaks[((size_t)rs * NSEG + lo) * SLOT + (k - off[lo])];
}

__global__ __launch_bounds__(256) void rowsum_kernel(
    const float* __restrict__ seg_peaks, const int* __restrict__ seg_counts,
    float* __restrict__ out)
{
    const int row = blockIdx.x;
    __shared__ int offP[NSEG + 1];
    __shared__ int offQ[NSEG + 1];
    __shared__ float red[256];

    const int tid  = threadIdx.x;
    const int lane = tid & 63;
    const int wave = tid >> 6;

    if (wave < 2) {
        const int rs = (wave == 0) ? row : (ROWS + row);
        int c = seg_counts[rs * NSEG + lane];
        int inc = c;
        #pragma unroll
        for (int d = 1; d < 64; d <<= 1) {
            int t = __shfl_up(inc, d);
            if (lane >= d) inc += t;
        }
        int* off = (wave == 0) ? offP : offQ;
        off[lane + 1] = inc;
        if (lane == 0) off[0] = 0;
    }
    __syncthreads();

    const int m  = offP[NSEG];
    const int n  = offQ[NSEG];
    const int mx = m > n ? m : n;

    float part = 0.0f;
    for (int j = tid; j < mx; j += 256) {
        float a = (j < m) ? get_peak(seg_peaks, offP, row,        m - 1 - j) : 0.0f;
        float b = (j < n) ? get_peak(seg_peaks, offQ, ROWS + row, n - 1 - j) : 0.0f;
        part += fabsf(a - b);
    }

    red[tid] = part;
    __syncthreads();
    for (int sft = 128; sft > 0; sft >>= 1) {
        if (tid < sft) red[tid] += red[tid + sft];
        __syncthreads();
    }
    if (tid == 0) {
        atomicAdd(out, red[0] * (1.0f / ((float)ROWS * (float)LEN)));
    }
}

extern "C" void kernel_launch(void* const* d_in, const int* in_sizes, int n_in,
                              void* d_out, int out_size, void* d_ws, size_t ws_size,
                              hipStream_t stream)
{
    const float* preds  = (const float*)d_in[0];
    const float* labels = (const float*)d_in[1];

    // ws layout: [ 64*64 segment peak lists (SLOT floats each) | 64*64 counts ]
    float* seg_peaks  = (float*)d_ws;
    int*   seg_counts = (int*)(seg_peaks + (size_t)2 * ROWS * NSEG * SLOT);

    hipMemsetAsync(d_out, 0, sizeof(float) * out_size, stream);
    peaks_seg_kernel<<<2 * ROWS * NSEG, THR1, 0, stream>>>(preds, labels,
                                                           seg_peaks, seg_counts);
    rowsum_kernel<<<ROWS, 256, 0, stream>>>(seg_peaks, seg_counts, (float*)d_out);
}

// Round 3
// 100.981 us; speedup vs baseline: 3.8342x; 1.1638x over previous
//
#include <hip/hip_runtime.h>
#include <hip/hip_bf16.h>
#include <float.h>

// Problem constants (from reference): B=32, L=131072, WIDTH=25, PAD=12.
#define ROWS 32
#define LEN  131072
#define PADW 12

#define SEG  2048            // segment length per block
#define NSEG (LEN / SEG)     // 64 segments per row-signal (== wave size, handy)
#define THR1 256             // threads in peaks kernel
#define PER  (SEG / THR1)    // 8 positions per thread
#define SLOT 160             // stride per segment peak list (max possible = 158)
#define NSLICE 16            // j-loop slices per row in rowsum kernel

// ---------------------------------------------------------------------------
// Kernel 1: segmented peak detection + per-segment stable compaction.
// Grid: 64 row-signals x 64 segments = 4096 blocks, 256 threads each.
// Peak predicate (== jnp.argmax(25-window)==PAD, first-max tie-break,
// validated rounds 1-2):
//   x[t] >  x[t-j]  for j=1..12
//   x[t] >= x[t+j]  for j=1..12
// with out-of-range treated as -FLT_MAX.
// ---------------------------------------------------------------------------
__global__ __launch_bounds__(THR1) void peaks_seg_kernel(
    const float* __restrict__ preds, const float* __restrict__ labels,
    float* __restrict__ seg_peaks, int* __restrict__ seg_counts)
{
    const int bid    = blockIdx.x;        // 0..4095
    const int rowsig = bid >> 6;          // 0..63 (0..31 preds, 32..63 labels)
    const int seg    = bid & (NSEG - 1);
    const float* __restrict__ x =
        (rowsig >= ROWS) ? labels + (size_t)(rowsig - ROWS) * LEN
                         : preds  + (size_t)rowsig * LEN;
    const int base = seg * SEG;

    __shared__ __align__(16) float s[SEG + 2 * PADW + 8]; // [base-12, base+SEG+12)
    __shared__ int wave_tot[THR1 / 64];

    const int tid  = threadIdx.x;
    const int lane = tid & 63;
    const int wave = tid >> 6;

    // stage segment + halo (coalesced)
    for (int i = tid; i < SEG + 2 * PADW; i += THR1) {
        int g = base + i - PADW;
        s[i] = ((unsigned)g < (unsigned)LEN) ? x[g] : -FLT_MAX;
    }
    __syncthreads();

    // 32-float register window covering positions tid*8-12 .. tid*8+19
    // (s index tid*8 .. tid*8+31); tid*8 floats = 32B-aligned -> ds_read_b128
    float w[32];
    {
        const float4* s4 = (const float4*)(s + tid * PER);
        #pragma unroll
        for (int k = 0; k < 8; ++k) {
            float4 t = s4[k];
            w[4 * k + 0] = t.x; w[4 * k + 1] = t.y;
            w[4 * k + 2] = t.z; w[4 * k + 3] = t.w;
        }
    }

    unsigned pmask = 0;
    #pragma unroll
    for (int p = 0; p < PER; ++p) {
        const float v = w[p + PADW];
        bool pk = true;
        #pragma unroll
        for (int j = 1; j <= PADW; ++j) pk = pk & (w[p + PADW - j] < v);
        #pragma unroll
        for (int j = 1; j <= PADW; ++j) pk = pk & (w[p + PADW + j] <= v);
        pmask |= (unsigned)pk << p;
    }
    const int cnt = __popc(pmask);

    // wave-level inclusive scan of per-thread counts
    int inc = cnt;
    #pragma unroll
    for (int d = 1; d < 64; d <<= 1) {
        int t = __shfl_up(inc, d);
        if (lane >= d) inc += t;
    }
    if (lane == 63) wave_tot[wave] = inc;
    __syncthreads();

    int wbase = 0;
    for (int wv = 0; wv < wave; ++wv) wbase += wave_tot[wv];
    int idx = wbase + (inc - cnt);

    float* __restrict__ pk_out = seg_peaks + (size_t)bid * SLOT;
    #pragma unroll
    for (int p = 0; p < PER; ++p) {
        if (pmask & (1u << p)) {
            pk_out[idx++] = (float)(base + tid * PER + p);
        }
    }

    if (tid == 0) {
        int tot = 0;
        #pragma unroll
        for (int wv = 0; wv < THR1 / 64; ++wv) tot += wave_tot[wv];
        seg_counts[bid] = tot;
    }
}

// ---------------------------------------------------------------------------
// Kernel 2: per-row back-aligned abs-diff sum, sliced across NSLICE blocks
// per row for latency hiding. Peaks are addressed through per-row
// segment-offset prefix sums (rebuilt per block -- 2 waves, shuffle scan)
// plus a 6-step binary search; no global compaction pass needed.
// sorted(where(is_peak,pos,0)) = [0]*(L-m) ++ P, so
//   sum = sum_j | (j<m ? P[m-1-j] : 0) - (j<n ? Q[n-1-j] : 0) |, j < max(m,n)
// Each block scales its partial by 1/(B*L) and atomically adds to out[0].
// ---------------------------------------------------------------------------
__device__ inline float get_peak(const float* __restrict__ seg_peaks,
                                 const int* __restrict__ off, int rs, int k)
{
    // find smallest seg with off[seg+1] > k
    int lo = 0, hi = NSEG - 1;
    while (lo < hi) {
        int mid = (lo + hi) >> 1;
        if (off[mid + 1] > k) hi = mid; else lo = mid + 1;
    }
    return seg_peaks[((size_t)rs * NSEG + lo) * SLOT + (k - off[lo])];
}

__global__ __launch_bounds__(256) void rowsum_kernel(
    const float* __restrict__ seg_peaks, const int* __restrict__ seg_counts,
    float* __restrict__ out)
{
    const int row   = blockIdx.x >> 4;        // 0..31
    const int slice = blockIdx.x & (NSLICE - 1);
    __shared__ int offP[NSEG + 1];
    __shared__ int offQ[NSEG + 1];
    __shared__ float red[256];

    const int tid  = threadIdx.x;
    const int lane = tid & 63;
    const int wave = tid >> 6;

    if (wave < 2) {
        const int rs = (wave == 0) ? row : (ROWS + row);
        int c = seg_counts[rs * NSEG + lane];
        int inc = c;
        #pragma unroll
        for (int d = 1; d < 64; d <<= 1) {
            int t = __shfl_up(inc, d);
            if (lane >= d) inc += t;
        }
        int* off = (wave == 0) ? offP : offQ;
        off[lane + 1] = inc;
        if (lane == 0) off[0] = 0;
    }
    __syncthreads();

    const int m  = offP[NSEG];
    const int n  = offQ[NSEG];
    const int mx = m > n ? m : n;

    // this block's j-slice
    const int chunk  = (mx + NSLICE - 1) / NSLICE;
    const int jbeg   = slice * chunk;
    const int jend   = (jbeg + chunk < mx) ? (jbeg + chunk) : mx;

    float part = 0.0f;
    for (int j = jbeg + tid; j < jend; j += 256) {
        float a = (j < m) ? get_peak(seg_peaks, offP, row,        m - 1 - j) : 0.0f;
        float b = (j < n) ? get_peak(seg_peaks, offQ, ROWS + row, n - 1 - j) : 0.0f;
        part += fabsf(a - b);
    }

    red[tid] = part;
    __syncthreads();
    for (int sft = 128; sft > 0; sft >>= 1) {
        if (tid < sft) red[tid] += red[tid + sft];
        __syncthreads();
    }
    if (tid == 0 && red[0] != 0.0f) {
        atomicAdd(out, red[0] * (1.0f / ((float)ROWS * (float)LEN)));
    }
}

extern "C" void kernel_launch(void* const* d_in, const int* in_sizes, int n_in,
                              void* d_out, int out_size, void* d_ws, size_t ws_size,
                              hipStream_t stream)
{
    const float* preds  = (const float*)d_in[0];
    const float* labels = (const float*)d_in[1];

    // ws layout: [ 64*64 segment peak lists (SLOT floats each) | 64*64 counts ]
    float* seg_peaks  = (float*)d_ws;
    int*   seg_counts = (int*)(seg_peaks + (size_t)2 * ROWS * NSEG * SLOT);

    hipMemsetAsync(d_out, 0, sizeof(float) * out_size, stream);
    peaks_seg_kernel<<<2 * ROWS * NSEG, THR1, 0, stream>>>(preds, labels,
                                                           seg_peaks, seg_counts);
    rowsum_kernel<<<ROWS * NSLICE, 256, 0, stream>>>(seg_peaks, seg_counts,
                                                     (float*)d_out);
}

// Round 4
// 87.435 us; speedup vs baseline: 4.4282x; 1.1549x over previous
//
#include <hip/hip_runtime.h>
#include <hip/hip_bf16.h>
#include <float.h>

// Problem constants (from reference): B=32, L=131072, WIDTH=25, PAD=12.
#define ROWS 32
#define LEN  131072
#define PADW 12

#define THR1  256            // threads in peaks kernel
#define PER   8              // positions per thread
#define BSEG  (THR1 * PER)   // 2048 positions per block
#define NBLK  (LEN / BSEG)   // 64 blocks per row-signal
#define WSEG  512            // positions per wave (64 lanes * 8)
#define NWSEG (LEN / WSEG)   // 256 wave-segments per row-signal
#define SLOTW 40             // max peaks in 512 positions: peaks >=13 apart -> ceil(512/13)=40
#define NSLICE 16            // j-loop slices per row in rowsum kernel
#define THR2  512            // threads in rowsum kernel (8 waves)

// ---------------------------------------------------------------------------
// Kernel 1: peak detection, no LDS, no barriers.
// Peak predicate (== jnp.argmax(25-window)==PAD, first-max tie-break,
// validated rounds 1-3):
//   x[t] >  x[t-j]  for j=1..12   <=>  x[t] >  max(x[t-12..t-1])
//   x[t] >= x[t+j]  for j=1..12   <=>  x[t] >= max(x[t+1..t+12])
// with out-of-range treated as -FLT_MAX. Sliding maxes via van Herk
// prefix/suffix decomposition (exact, same semantics).
// Compaction is wave-granular: each wave owns a 512-position segment and
// writes its peaks (ascending) to a private SLOTW-stride list.
// ---------------------------------------------------------------------------
__global__ __launch_bounds__(THR1) void peaks_wave_kernel(
    const float* __restrict__ preds, const float* __restrict__ labels,
    float* __restrict__ seg_peaks, int* __restrict__ seg_counts)
{
    const int bid    = blockIdx.x;        // 0..4095
    const int rowsig = bid >> 6;          // 0..63 (0..31 preds, 32..63 labels)
    const int segb   = bid & (NBLK - 1);
    const float* __restrict__ x =
        (rowsig >= ROWS) ? labels + (size_t)(rowsig - ROWS) * LEN
                         : preds  + (size_t)rowsig * LEN;

    const int tid  = threadIdx.x;
    const int lane = tid & 63;
    const int wave = tid >> 6;
    const int p0   = segb * BSEG + tid * PER;   // first position owned

    // 32-float window covering x[p0-12 .. p0+19]; p0-12 is 16B-aligned.
    float w[32];
    if (p0 >= PADW && p0 + 20 <= LEN) {
        const float4* __restrict__ g4 = (const float4*)(x + p0 - PADW);
        #pragma unroll
        for (int k = 0; k < 8; ++k) {
            float4 t = g4[k];
            w[4 * k + 0] = t.x; w[4 * k + 1] = t.y;
            w[4 * k + 2] = t.z; w[4 * k + 3] = t.w;
        }
    } else {
        #pragma unroll
        for (int i = 0; i < 32; ++i) {
            int g = p0 - PADW + i;
            w[i] = ((unsigned)g < (unsigned)LEN) ? x[g] : -FLT_MAX;
        }
    }

    // van Herk: SA[i]=max(w[i..11]), PB[t]=max(w[12..12+t]),
    //           SC[i]=max(w[13+i..24]), PD[t]=max(w[25..25+t])
    float SA[8], SC[8], PB[7], PD[7];
    {
        float r = fmaxf(fmaxf(w[11], w[10]), fmaxf(w[9], w[8]));
        SA[7] = fmaxf(r, w[7]);
        #pragma unroll
        for (int i = 6; i >= 0; --i) SA[i] = fmaxf(SA[i + 1], w[i]);
    }
    {
        PB[0] = w[12];
        #pragma unroll
        for (int t = 1; t < 7; ++t) PB[t] = fmaxf(PB[t - 1], w[12 + t]);
    }
    {
        float r = fmaxf(fmaxf(w[24], w[23]), fmaxf(w[22], w[21]));
        SC[7] = fmaxf(r, w[20]);
        #pragma unroll
        for (int i = 6; i >= 0; --i) SC[i] = fmaxf(SC[i + 1], w[13 + i]);
    }
    {
        PD[0] = w[25];
        #pragma unroll
        for (int t = 1; t < 7; ++t) PD[t] = fmaxf(PD[t - 1], w[25 + t]);
    }

    unsigned pmask = 0;
    #pragma unroll
    for (int j = 0; j < PER; ++j) {
        const float v  = w[12 + j];
        const float mp = (j == 0) ? SA[0] : fmaxf(SA[j], PB[j - 1]);
        const float mn = (j == 0) ? SC[0] : fmaxf(SC[j], PD[j - 1]);
        bool pk = (v > mp) & (v >= mn);
        pmask |= (unsigned)pk << j;
    }
    const int cnt = __popc(pmask);

    // wave-level inclusive scan of per-thread counts
    int inc = cnt;
    #pragma unroll
    for (int d = 1; d < 64; d <<= 1) {
        int t = __shfl_up(inc, d);
        if (lane >= d) inc += t;
    }
    const int wtot = __shfl(inc, 63);

    const int wseg = segb * 4 + wave;     // 0..255 within rowsig
    float* __restrict__ pk_out =
        seg_peaks + ((size_t)rowsig * NWSEG + wseg) * SLOTW;
    int idx = inc - cnt;                  // exclusive prefix within wave
    #pragma unroll
    for (int p = 0; p < PER; ++p) {
        if (pmask & (1u << p)) pk_out[idx++] = (float)(p0 + p);
    }
    if (lane == 0) seg_counts[rowsig * NWSEG + wseg] = wtot;
}

// ---------------------------------------------------------------------------
// Kernel 2: per-row back-aligned abs-diff sum, sliced across NSLICE blocks.
// Each block rebuilds the 256-entry wave-segment offset prefix for both
// signals (8 waves, shuffle scan + cross-wave fixup), then sums its j-slice,
// addressing the k-th peak via binary search (depth 8) + segment list.
// sorted(where(is_peak,pos,0)) = [0]*(L-m) ++ P, so
//   sum = sum_j | (j<m ? P[m-1-j] : 0) - (j<n ? Q[n-1-j] : 0) |, j < max(m,n)
// Each block scales its partial by 1/(B*L) and atomically adds to out[0].
// ---------------------------------------------------------------------------
__device__ inline float get_peak(const float* __restrict__ seg_peaks,
                                 const int* __restrict__ off, int rs, int k)
{
    int lo = 0, hi = NWSEG - 1;           // smallest seg with off[seg+1] > k
    while (lo < hi) {
        int mid = (lo + hi) >> 1;
        if (off[mid + 1] > k) hi = mid; else lo = mid + 1;
    }
    return seg_peaks[((size_t)rs * NWSEG + lo) * SLOTW + (k - off[lo])];
}

__global__ __launch_bounds__(THR2) void rowsum_kernel(
    const float* __restrict__ seg_peaks, const int* __restrict__ seg_counts,
    float* __restrict__ out)
{
    const int row   = blockIdx.x >> 4;        // 0..31
    const int slice = blockIdx.x & (NSLICE - 1);
    __shared__ int offP[NWSEG + 1];
    __shared__ int offQ[NWSEG + 1];
    __shared__ int wsum[8];
    __shared__ float fred[8];

    const int tid  = threadIdx.x;
    const int lane = tid & 63;
    const int wave = tid >> 6;                // 0..7
    const int sig  = wave >> 2;               // 0: preds, 1: labels
    const int sidx = (wave & 3) * 64 + lane;  // 0..255
    const int rs   = sig ? (ROWS + row) : row;

    int c = seg_counts[rs * NWSEG + sidx];
    int inc = c;
    #pragma unroll
    for (int d = 1; d < 64; d <<= 1) {
        int t = __shfl_up(inc, d);
        if (lane >= d) inc += t;
    }
    if (lane == 63) wsum[wave] = inc;
    __syncthreads();

    int pre = 0;
    for (int wv = sig * 4; wv < wave; ++wv) pre += wsum[wv];
    int* off = sig ? offQ : offP;
    off[sidx + 1] = inc + pre;
    if (tid == 0) { offP[0] = 0; offQ[0] = 0; }
    __syncthreads();

    const int m  = offP[NWSEG];
    const int n  = offQ[NWSEG];
    const int mx = m > n ? m : n;

    const int chunk = (mx + NSLICE - 1) / NSLICE;
    const int jbeg  = slice * chunk;
    const int jend  = (jbeg + chunk < mx) ? (jbeg + chunk) : mx;

    float part = 0.0f;
    for (int j = jbeg + tid; j < jend; j += THR2) {
        float a = (j < m) ? get_peak(seg_peaks, offP, row,        m - 1 - j) : 0.0f;
        float b = (j < n) ? get_peak(seg_peaks, offQ, ROWS + row, n - 1 - j) : 0.0f;
        part += fabsf(a - b);
    }

    // per-wave reduce, then wave 0 lane 0 accumulates
    #pragma unroll
    for (int d = 32; d > 0; d >>= 1) part += __shfl_down(part, d);
    if (lane == 0) fred[wave] = part;
    __syncthreads();
    if (tid == 0) {
        float s = 0.0f;
        #pragma unroll
        for (int wv = 0; wv < 8; ++wv) s += fred[wv];
        if (s != 0.0f)
            atomicAdd(out, s * (1.0f / ((float)ROWS * (float)LEN)));
    }
}

extern "C" void kernel_launch(void* const* d_in, const int* in_sizes, int n_in,
                              void* d_out, int out_size, void* d_ws, size_t ws_size,
                              hipStream_t stream)
{
    const float* preds  = (const float*)d_in[0];
    const float* labels = (const float*)d_in[1];

    // ws layout: [ 64*256 wave-segment peak lists (SLOTW floats) | 64*256 counts ]
    float* seg_peaks  = (float*)d_ws;
    int*   seg_counts = (int*)(seg_peaks + (size_t)2 * ROWS * NWSEG * SLOTW);

    hipMemsetAsync(d_out, 0, sizeof(float) * out_size, stream);
    peaks_wave_kernel<<<2 * ROWS * NBLK, THR1, 0, stream>>>(preds, labels,
                                                            seg_peaks, seg_counts);
    rowsum_kernel<<<ROWS * NSLICE, THR2, 0, stream>>>(seg_peaks, seg_counts,
                                                      (float*)d_out);
}

// Round 5
// 85.210 us; speedup vs baseline: 4.5438x; 1.0261x over previous
//
#include <hip/hip_runtime.h>
#include <hip/hip_bf16.h>
#include <float.h>

// Problem constants (from reference): B=32, L=131072, WIDTH=25, PAD=12.
#define ROWS 32
#define LEN  131072
#define PADW 12

#define THR1  256            // threads in peaks kernel
#define PER   8              // positions per thread (<=12 => at most ONE peak/thread)
#define BSEG  (THR1 * PER)   // 2048 positions per block
#define NBLK  (LEN / BSEG)   // 64 blocks per row-signal
#define WSEG  512            // positions per wave (64 lanes * 8)
#define NWSEG (LEN / WSEG)   // 256 wave-segments per row-signal
#define SLOTW 40             // max peaks in 512 positions: peaks >=13 apart -> ceil(512/13)=40
#define NSLICE 16            // j-loop slices per row in rowsum kernel
#define THR2  512            // threads in rowsum kernel (8 waves)

// ---------------------------------------------------------------------------
// Kernel 1: peak detection, no LDS, no barriers, no scan.
// Peak predicate (== jnp.argmax(25-window)==PAD, first-max tie-break,
// validated rounds 1-4):
//   x[t] >  x[t-j]  for j=1..12   <=>  x[t] >  max(x[t-12..t-1])
//   x[t] >= x[t+j]  for j=1..12   <=>  x[t] >= max(x[t+1..t+12])
// with out-of-range treated as -FLT_MAX. Sliding maxes via van Herk
// prefix/suffix decomposition (exact, same semantics).
// Peaks are >=13 apart (t1 peak => x[t1]>=x[t1+1..t1+12]; t2 peak <=12 later
// => x[t2]>x[t2-12..t2-1] -- contradiction), so each 8-position thread has
// at most ONE peak: compaction is ballot + popc-rank + one predicated store.
// Block 0 also zeroes d_out (runs before rowsum by kernel ordering), so no
// separate memset dispatch is needed.
// ---------------------------------------------------------------------------
__global__ __launch_bounds__(THR1) void peaks_wave_kernel(
    const float* __restrict__ preds, const float* __restrict__ labels,
    float* __restrict__ seg_peaks, int* __restrict__ seg_counts,
    float* __restrict__ out, int out_size)
{
    const int bid    = blockIdx.x;        // 0..4095
    const int rowsig = bid >> 6;          // 0..63 (0..31 preds, 32..63 labels)
    const int segb   = bid & (NBLK - 1);
    const float* __restrict__ x =
        (rowsig >= ROWS) ? labels + (size_t)(rowsig - ROWS) * LEN
                         : preds  + (size_t)rowsig * LEN;

    const int tid  = threadIdx.x;
    const int lane = tid & 63;
    const int wave = tid >> 6;
    const int p0   = segb * BSEG + tid * PER;   // first position owned

    if (bid == 0) {
        for (int i = tid; i < out_size; i += THR1) out[i] = 0.0f;
    }

    // 32-float window covering x[p0-12 .. p0+19]; (p0-12)*4 is 16B-aligned.
    float w[32];
    if (p0 >= PADW && p0 + 20 <= LEN) {
        const float4* __restrict__ g4 = (const float4*)(x + p0 - PADW);
        #pragma unroll
        for (int k = 0; k < 8; ++k) {
            float4 t = g4[k];
            w[4 * k + 0] = t.x; w[4 * k + 1] = t.y;
            w[4 * k + 2] = t.z; w[4 * k + 3] = t.w;
        }
    } else {
        #pragma unroll
        for (int i = 0; i < 32; ++i) {
            int g = p0 - PADW + i;
            w[i] = ((unsigned)g < (unsigned)LEN) ? x[g] : -FLT_MAX;
        }
    }

    // van Herk: SA[i]=max(w[i..11]), PB[t]=max(w[12..12+t]),
    //           SC[i]=max(w[13+i..24]), PD[t]=max(w[25..25+t])
    float SA[8], SC[8], PB[7], PD[7];
    {
        float r = fmaxf(fmaxf(w[11], w[10]), fmaxf(w[9], w[8]));
        SA[7] = fmaxf(r, w[7]);
        #pragma unroll
        for (int i = 6; i >= 0; --i) SA[i] = fmaxf(SA[i + 1], w[i]);
    }
    {
        PB[0] = w[12];
        #pragma unroll
        for (int t = 1; t < 7; ++t) PB[t] = fmaxf(PB[t - 1], w[12 + t]);
    }
    {
        float r = fmaxf(fmaxf(w[24], w[23]), fmaxf(w[22], w[21]));
        SC[7] = fmaxf(r, w[20]);
        #pragma unroll
        for (int i = 6; i >= 0; --i) SC[i] = fmaxf(SC[i + 1], w[13 + i]);
    }
    {
        PD[0] = w[25];
        #pragma unroll
        for (int t = 1; t < 7; ++t) PD[t] = fmaxf(PD[t - 1], w[25 + t]);
    }

    unsigned pmask = 0;
    #pragma unroll
    for (int j = 0; j < PER; ++j) {
        const float v  = w[12 + j];
        const float mp = (j == 0) ? SA[0] : fmaxf(SA[j], PB[j - 1]);
        const float mn = (j == 0) ? SC[0] : fmaxf(SC[j], PD[j - 1]);
        bool pk = (v > mp) & (v >= mn);
        pmask |= (unsigned)pk << j;
    }

    // at most one bit set in pmask -> ballot-based compaction, one store
    const bool has = (pmask != 0);
    const unsigned long long bmask = __ballot(has);
    const int rank = __popcll(bmask & ((1ull << lane) - 1ull));
    const int wseg = segb * 4 + wave;     // 0..255 within rowsig
    float* __restrict__ pk_out =
        seg_peaks + ((size_t)rowsig * NWSEG + wseg) * SLOTW;
    if (has) pk_out[rank] = (float)(p0 + __ffs(pmask) - 1);
    if (lane == 0) seg_counts[rowsig * NWSEG + wseg] = __popcll(bmask);
}

// ---------------------------------------------------------------------------
// Kernel 2: per-row back-aligned abs-diff sum, sliced across NSLICE blocks.
// Each block rebuilds the 256-entry wave-segment offset prefix for both
// signals (8 waves, shuffle scan + cross-wave fixup), then sums its j-slice,
// addressing the k-th peak via binary search (depth 8) + segment list.
// sorted(where(is_peak,pos,0)) = [0]*(L-m) ++ P, so
//   sum = sum_j | (j<m ? P[m-1-j] : 0) - (j<n ? Q[n-1-j] : 0) |, j < max(m,n)
// Each block scales its partial by 1/(B*L) and atomically adds to out[0]
// (zeroed by peaks kernel block 0).
// ---------------------------------------------------------------------------
__device__ inline float get_peak(const float* __restrict__ seg_peaks,
                                 const int* __restrict__ off, int rs, int k)
{
    int lo = 0, hi = NWSEG - 1;           // smallest seg with off[seg+1] > k
    while (lo < hi) {
        int mid = (lo + hi) >> 1;
        if (off[mid + 1] > k) hi = mid; else lo = mid + 1;
    }
    return seg_peaks[((size_t)rs * NWSEG + lo) * SLOTW + (k - off[lo])];
}

__global__ __launch_bounds__(THR2) void rowsum_kernel(
    const float* __restrict__ seg_peaks, const int* __restrict__ seg_counts,
    float* __restrict__ out)
{
    const int row   = blockIdx.x >> 4;        // 0..31
    const int slice = blockIdx.x & (NSLICE - 1);
    __shared__ int offP[NWSEG + 1];
    __shared__ int offQ[NWSEG + 1];
    __shared__ int wsum[8];
    __shared__ float fred[8];

    const int tid  = threadIdx.x;
    const int lane = tid & 63;
    const int wave = tid >> 6;                // 0..7
    const int sig  = wave >> 2;               // 0: preds, 1: labels
    const int sidx = (wave & 3) * 64 + lane;  // 0..255
    const int rs   = sig ? (ROWS + row) : row;

    int c = seg_counts[rs * NWSEG + sidx];
    int inc = c;
    #pragma unroll
    for (int d = 1; d < 64; d <<= 1) {
        int t = __shfl_up(inc, d);
        if (lane >= d) inc += t;
    }
    if (lane == 63) wsum[wave] = inc;
    __syncthreads();

    int pre = 0;
    for (int wv = sig * 4; wv < wave; ++wv) pre += wsum[wv];
    int* off = sig ? offQ : offP;
    off[sidx + 1] = inc + pre;
    if (tid == 0) { offP[0] = 0; offQ[0] = 0; }
    __syncthreads();

    const int m  = offP[NWSEG];
    const int n  = offQ[NWSEG];
    const int mx = m > n ? m : n;

    const int chunk = (mx + NSLICE - 1) / NSLICE;
    const int jbeg  = slice * chunk;
    const int jend  = (jbeg + chunk < mx) ? (jbeg + chunk) : mx;

    float part = 0.0f;
    for (int j = jbeg + tid; j < jend; j += THR2) {
        float a = (j < m) ? get_peak(seg_peaks, offP, row,        m - 1 - j) : 0.0f;
        float b = (j < n) ? get_peak(seg_peaks, offQ, ROWS + row, n - 1 - j) : 0.0f;
        part += fabsf(a - b);
    }

    // per-wave reduce, then one atomic per block
    #pragma unroll
    for (int d = 32; d > 0; d >>= 1) part += __shfl_down(part, d);
    if (lane == 0) fred[wave] = part;
    __syncthreads();
    if (tid == 0) {
        float s = 0.0f;
        #pragma unroll
        for (int wv = 0; wv < 8; ++wv) s += fred[wv];
        if (s != 0.0f)
            atomicAdd(out, s * (1.0f / ((float)ROWS * (float)LEN)));
    }
}

extern "C" void kernel_launch(void* const* d_in, const int* in_sizes, int n_in,
                              void* d_out, int out_size, void* d_ws, size_t ws_size,
                              hipStream_t stream)
{
    const float* preds  = (const float*)d_in[0];
    const float* labels = (const float*)d_in[1];

    // ws layout: [ 64*256 wave-segment peak lists (SLOTW floats) | 64*256 counts ]
    float* seg_peaks  = (float*)d_ws;
    int*   seg_counts = (int*)(seg_peaks + (size_t)2 * ROWS * NWSEG * SLOTW);

    peaks_wave_kernel<<<2 * ROWS * NBLK, THR1, 0, stream>>>(
        preds, labels, seg_peaks, seg_counts, (float*)d_out, out_size);
    rowsum_kernel<<<ROWS * NSLICE, THR2, 0, stream>>>(seg_peaks, seg_counts,
                                                      (float*)d_out);
}